// Round 15
// baseline (179.344 us; speedup 1.0000x reference)
//
#include <hip/hip_runtime.h>
#include <cfloat>
#include <climits>

#define NEG 0.2f
#define GEPS 1e-5f
#define D 6
#define H 13   // 2*D+1
#define KOUT 16

#define MPAD 8192      // padded candidate capacity (NTILES*TILE)
#define TILE 1024      // candidates per LDS tile (16 KB)
#define NTILES 8       // MPAD / TILE
#define P1TILES 4      // tiles scanned in pass 1 (subset threshold — still a
                       // provable upper bound; E[survivors] ~= 2*KSEL)
#define QW 8           // queries per wave
#define QBLK 32        // queries per block (4 waves)
#define CAP 64         // survivor slots per query
#define KMAX 17        // max KSEL (atom task)
#define MARGIN 0.05f   // e-space margin covering fma-vs-reference rounding

__device__ __forceinline__ float lrelu(float x){ return x >= 0.f ? x : NEG*x; }

// fused prep: pack atoms (padded) + pack points + atomtype MLP
__global__ void prep_kernel(const float* __restrict__ atom_xyz,
                            const float* __restrict__ xyz,
                            const float* __restrict__ at_in,
                            const float* __restrict__ w1, const float* __restrict__ b1,
                            const float* __restrict__ w2, const float* __restrict__ b2,
                            float4* __restrict__ candP, float4* __restrict__ ptsP,
                            float* __restrict__ fa, int n_at, int n_pts){
  int i = blockIdx.x*blockDim.x + threadIdx.x;
  if (i < MPAD){
    if (i < n_at){
      float x = atom_xyz[3*i], y = atom_xyz[3*i+1], z = atom_xyz[3*i+2];
      float sq;
      {
#pragma clang fp contract(off)
        sq = (x*x + y*y) + z*z;
      }
      candP[i] = make_float4(x,y,z,sq);
    } else {
      candP[i] = make_float4(0.f,0.f,0.f,1e30f); // never a min/survivor
    }
  }
  if (i < n_pts){
    float x = xyz[3*i], y = xyz[3*i+1], z = xyz[3*i+2];
    float sq;
    {
#pragma clang fp contract(off)
      sq = (x*x + y*y) + z*z;
    }
    ptsP[i] = make_float4(x,y,z,sq);
  }
  if (i < n_at){
    float x[D], h[D];
    #pragma unroll
    for (int j=0;j<D;j++) x[j] = at_in[i*D+j];
    #pragma unroll
    for (int o=0;o<D;o++){
      float acc = b1[o];
      #pragma unroll
      for (int j=0;j<D;j++) acc += w1[o*D+j]*x[j];
      h[o] = lrelu(acc);
    }
    #pragma unroll
    for (int o=0;o<D;o++){
      float acc = b2[o];
      #pragma unroll
      for (int j=0;j<D;j++) acc += w2[o*D+j]*h[j];
      fa[i*D+o] = acc;
    }
  }
}

// QW independent ascending value-sorts across 64 lanes (ILP-batched)
__device__ __forceinline__ void sort64fq(float (&v)[QW], int lane){
  #pragma unroll
  for (int k = 2; k <= 64; k <<= 1){
    #pragma unroll
    for (int j = k >> 1; j >= 1; j >>= 1){
      bool dir = ((lane & j) == 0) == ((lane & k) == 0);
      #pragma unroll
      for (int q = 0; q < QW; ++q){
        float o = __shfl_xor(v[q], j);
        v[q] = dir ? fminf(v[q], o) : fmaxf(v[q], o);
      }
    }
  }
}

// ascending value bitonic sort across 64 lanes
__device__ __forceinline__ void sort64f1(float& a, int lane){
  #pragma unroll
  for (int k=2;k<=64;k<<=1){
    #pragma unroll
    for (int j=k>>1;j>=1;j>>=1){
      float o = __shfl_xor(a, j);
      bool dir = ((lane&j)==0)==((lane&k)==0);
      a = dir ? fminf(a,o) : fmaxf(a,o);
    }
  }
}

// ascending lexicographic (d, i) bitonic sort across 64 lanes
__device__ __forceinline__ void sort64pair(float& d, int& i, int lane){
  #pragma unroll
  for (int k = 2; k <= 64; k <<= 1){
    #pragma unroll
    for (int j = k >> 1; j >= 1; j >>= 1){
      float od = __shfl_xor(d, j);
      int   oi = __shfl_xor(i, j);
      bool lower = (lane & j) == 0;
      bool asc   = (lane & k) == 0;
      bool oless = (od < d) || (od == d && oi < i);
      bool take  = (lower == asc) ? oless : !oless;
      d = take ? od : d;
      i = take ? oi : i;
    }
  }
}

// KNN v10: R14's fused LDS-tiled kernel with pass 1 on a HALF-subset.
// Upper-bound argument: T(q) = ksel-th smallest of the 64 per-lane e-mins
// over the subset (64 disjoint lane sets => ksel distinct witnesses with
// e <= T), and the true ksel-th over the full set is <= the subset's, so
// pass 2 (full scan, e <= T + handled by MARGIN at the exact-rescore level)
// still contains the exact top-ksel. Looser T only ADDS survivors
// (E ~= 2*ksel ~= 34 << CAP). Overflow fallback is the wave-parallel exact
// rescan (R12-proven), not lane-0 serial.
__global__ __launch_bounds__(256)
void knn10_kernel(const float4* __restrict__ candP, int ncand,
                  const float4* __restrict__ qarrA, int nqA, int nbA,
                  const float4* __restrict__ qarrB, int nqB,
                  int* __restrict__ oidxA, float* __restrict__ odistA,
                  int* __restrict__ oidxB, float* __restrict__ odistB){
  __shared__ float4 tile[TILE];            // 16 KB
  __shared__ float4 qs[QBLK];
  __shared__ ushort slots[4][QW][CAP];     // 4 KB
  __shared__ int    scnt[4][QW];

  const int tid  = threadIdx.x;
  const int w    = tid >> 6;
  const int lane = tid & 63;

  const bool taskA = (int)blockIdx.x < nbA;
  const int  bq    = taskA ? blockIdx.x : (blockIdx.x - nbA);
  const float4* __restrict__ qarr = taskA ? qarrA : qarrB;
  const int  nq    = taskA ? nqA : nqB;
  const int  ksel  = taskA ? 17 : 16;
  const int  ooff  = taskA ? 1  : 0;
  int*   __restrict__ oidx  = taskA ? oidxA  : oidxB;
  float* __restrict__ odist = taskA ? odistA : odistB;

  if (tid < QBLK){
    int qg = bq*QBLK + tid;
    qs[tid] = qarr[qg < nq ? qg : nq-1];   // clamp: all waves stay full
  }
  if (lane < QW) scnt[w][lane] = 0;
  __syncthreads();

  // -2*q in registers (e = fma(q2x,cx, fma(q2y,cy, fma(q2z,cz, cw))))
  float q2x[QW], q2y[QW], q2z[QW];
  #pragma unroll
  for (int q = 0; q < QW; ++q){
    float4 v = qs[w*QW + q];
    q2x[q] = -2.f*v.x; q2y[q] = -2.f*v.y; q2z[q] = -2.f*v.z;
  }

  // ------- pass 1: per-lane e-min per query over P1TILES subset ---------
  float mn[QW];
  #pragma unroll
  for (int q = 0; q < QW; ++q) mn[q] = FLT_MAX;

  for (int t = 0; t < P1TILES; ++t){
    #pragma unroll
    for (int u = 0; u < TILE/256; ++u)
      tile[tid + 256*u] = candP[t*TILE + tid + 256*u];
    __syncthreads();
    #pragma unroll 2
    for (int i = 0; i < TILE/64; ++i){
      float4 cv = tile[i*64 + lane];
      #pragma unroll
      for (int q = 0; q < QW; ++q){
        float e = fmaf(q2x[q], cv.x, fmaf(q2y[q], cv.y, fmaf(q2z[q], cv.z, cv.w)));
        mn[q] = fminf(mn[q], e);
      }
    }
    __syncthreads();
  }

  // threshold per query: ksel-th smallest lane-min (subset) + margin
  sort64fq(mn, lane);
  float T[QW];
  #pragma unroll
  for (int q = 0; q < QW; ++q) T[q] = __shfl(mn[q], ksel-1) + MARGIN;

  // ---------------- pass 2: collect survivors (full scan) ----------------
  for (int t = 0; t < NTILES; ++t){
    #pragma unroll
    for (int u = 0; u < TILE/256; ++u)
      tile[tid + 256*u] = candP[t*TILE + tid + 256*u];
    __syncthreads();
    #pragma unroll 2
    for (int i = 0; i < TILE/64; ++i){
      float4 cv = tile[i*64 + lane];
      const int j = t*TILE + i*64 + lane;
      #pragma unroll
      for (int q = 0; q < QW; ++q){
        float e = fmaf(q2x[q], cv.x, fmaf(q2y[q], cv.y, fmaf(q2z[q], cv.z, cv.w)));
        if (e <= T[q]){
          int ofs = atomicAdd(&scnt[w][q], 1);
          if (ofs < CAP) slots[w][q][ofs] = (ushort)j;
        }
      }
    }
    __syncthreads();
  }

  // ---------------- phase 3: exact per-query select ----------------
  for (int q = 0; q < QW; ++q){
    const int qgq = bq*QBLK + w*QW + q;
    if (qgq >= nq) continue;                 // wave-uniform
    const float4 qv = qs[w*QW + q];
    int C = scnt[w][q];

    if (C > CAP){
      // wave-parallel exact fallback (R12-proven): full rescan, own
      // full-set threshold, ballot-compact into this query's slots.
      const float fq2x = -2.f*qv.x, fq2y = -2.f*qv.y, fq2z = -2.f*qv.z;
      float m = FLT_MAX;
      for (int j = lane; j < MPAD; j += 64){
        float4 cp = candP[j];
        float e = fmaf(fq2x, cp.x, fmaf(fq2y, cp.y, fmaf(fq2z, cp.z, cp.w)));
        m = fminf(m, e);
      }
      sort64f1(m, lane);
      const float T2 = __shfl(m, ksel-1) + MARGIN;
      int cnt = 0;
      const unsigned long long ltm = (1ULL << lane) - 1ULL;
      for (int j = lane; j < MPAD; j += 64){
        float4 cp = candP[j];
        float e = fmaf(fq2x, cp.x, fmaf(fq2y, cp.y, fmaf(fq2z, cp.z, cp.w)));
        bool acc = e <= T2;
        unsigned long long msk = __ballot(acc);
        if (acc){
          int ofs = cnt + __popcll(msk & ltm);
          if (ofs < CAP) slots[w][q][ofs] = (ushort)j;
        }
        cnt += __popcll(msk);
      }
      __threadfence_block();
      C = cnt;
    }

    if (C <= CAP){
      int g = INT_MAX; float d2 = FLT_MAX;
      if (lane < C){
        g = slots[w][q][lane];
        float4 cp = candP[g];
        {
#pragma clang fp contract(off)
          float dot = qv.x*cp.x + qv.y*cp.y + qv.z*cp.z;
          d2 = (qv.w + cp.w) - 2.0f*dot;
        }
      }
      sort64pair(d2, g, lane);
      if (lane >= ooff && lane < ooff + KOUT){
        float4 cp = candP[g];
        float dist;
        {
#pragma clang fp contract(off)
          float dx = qv.x-cp.x, dy = qv.y-cp.y, dz = qv.z-cp.z;
          dist = (dx*dx + dy*dy) + dz*dz;
        }
        oidx[(size_t)qgq*KOUT + (lane-ooff)]  = g;
        odist[(size_t)qgq*KOUT + (lane-ooff)] = dist;
      }
    } else if (lane == 0){
      // astronomically rare double overflow: serial exact full scan
      float bd[KMAX]; int bi[KMAX];
      for (int t=0;t<ksel;t++){ bd[t]=FLT_MAX; bi[t]=INT_MAX; }
      float cmd = FLT_MAX; int cmi = INT_MAX;
      for (int jj = 0; jj < ncand; ++jj){
        float4 cp = candP[jj];
        float d2;
        {
#pragma clang fp contract(off)
          float dot = qv.x*cp.x + qv.y*cp.y + qv.z*cp.z;
          d2 = (qv.w + cp.w) - 2.0f*dot;
        }
        if (d2 < cmd || (d2 == cmd && jj < cmi)){
          int rt = 0; float rmd=-FLT_MAX; int rmi=-1;
          for (int t=0;t<ksel;t++){
            if (bd[t] > rmd || (bd[t]==rmd && bi[t]>rmi)){ rmd=bd[t]; rmi=bi[t]; rt=t; }
          }
          bd[rt]=d2; bi[rt]=jj;
          cmd=-FLT_MAX; cmi=-1;
          for (int t=0;t<ksel;t++){
            if (bd[t] > cmd || (bd[t]==cmd && bi[t]>cmi)){ cmd=bd[t]; cmi=bi[t]; }
          }
        }
      }
      for (int t=0;t<ksel;t++){
        int rt=-1; float mnd=FLT_MAX; int mni=INT_MAX;
        for (int u2=0;u2<ksel;u2++){
          if (bd[u2] < mnd || (bd[u2]==mnd && bi[u2]<mni)){ mnd=bd[u2]; mni=bi[u2]; rt=u2; }
        }
        bd[rt]=FLT_MAX; bi[rt]=INT_MAX;
        if (t >= ooff){
          float4 cp = candP[mni];
          float dist;
          {
#pragma clang fp contract(off)
            float dx=qv.x-cp.x, dy=qv.y-cp.y, dz=qv.z-cp.z;
            dist = (dx*dx + dy*dy) + dz*dz;
          }
          oidx[(size_t)qgq*KOUT + (t-ooff)]  = mni;
          odist[(size_t)qgq*KOUT + (t-ooff)] = dist;
        }
      }
    }
  }
}

// One message-passing block: out = self + lrelu(groupnorm(sum_k MLP(feat_k)))
// 4 threads per point: each handles 4 of the 16 neighbors, shfl-reduce.
template<bool SELF_ONES>
__global__ __launch_bounds__(256)
void mp_kernel(const float* __restrict__ self_feat,
               const float* __restrict__ nb_src,
               const int* __restrict__ idx,
               const float* __restrict__ dists,
               const float* __restrict__ w1g, const float* __restrict__ b1g,
               const float* __restrict__ w2g, const float* __restrict__ b2g,
               const float* __restrict__ gam, const float* __restrict__ bet,
               float* __restrict__ out, int n){
  __shared__ float w1[H*H], b1v[H], w2[D*H], b2v[D], gm[D], bt[D];
  for (int t=threadIdx.x; t<H*H; t+=blockDim.x) w1[t]=w1g[t];
  if (threadIdx.x < H) b1v[threadIdx.x]=b1g[threadIdx.x];
  for (int t=threadIdx.x; t<D*H; t+=blockDim.x) w2[t]=w2g[t];
  if (threadIdx.x < D){
    b2v[threadIdx.x]=b2g[threadIdx.x];
    gm[threadIdx.x]=gam[threadIdx.x];
    bt[threadIdx.x]=bet[threadIdx.x];
  }
  __syncthreads();
  int tt = blockIdx.x*blockDim.x + threadIdx.x;
  int p = tt >> 2, sub = tt & 3;
  if (p >= n) return;

  float s[D];
  #pragma unroll
  for (int j=0;j<D;j++) s[j] = SELF_ONES ? 1.0f : self_feat[p*D+j];
  float msg[D] = {0,0,0,0,0,0};

  #pragma unroll
  for (int u=0;u<KOUT/4;u++){
    int k = u*4 + sub;
    int j = idx[p*KOUT+k];
    float dd = dists[p*KOUT+k];
    float f[H];
    #pragma unroll
    for (int c=0;c<D;c++) f[c]=s[c];
    #pragma unroll
    for (int c=0;c<D;c++) f[D+c]=nb_src[j*D+c];
    f[2*D]=dd;
    float h[H];
    #pragma unroll
    for (int o=0;o<H;o++){
      float acc=b1v[o];
      #pragma unroll
      for (int c=0;c<H;c++) acc += w1[o*H+c]*f[c];
      h[o]=lrelu(acc);
    }
    #pragma unroll
    for (int o=0;o<D;o++){
      float acc=b2v[o];
      #pragma unroll
      for (int c=0;c<H;c++) acc += w2[o*H+c]*h[c];
      msg[o]+=acc;
    }
  }

  #pragma unroll
  for (int c=0;c<D;c++){
    msg[c] += __shfl_xor(msg[c], 1);
    msg[c] += __shfl_xor(msg[c], 2);
  }

  if (sub == 0){
    float y[D];
    #pragma unroll
    for (int gi=0; gi<2; gi++){
      float m0=msg[gi*3+0], m1=msg[gi*3+1], m2=msg[gi*3+2];
      float mu = ((m0+m1)+m2) / 3.0f;
      float d0=m0-mu, d1=m1-mu, d2v=m2-mu;
      float var = ((d0*d0 + d1*d1) + d2v*d2v) / 3.0f;
      float inv = 1.0f / sqrtf(var + GEPS);
      y[gi*3+0] = d0*inv;
      y[gi*3+1] = d1*inv;
      y[gi*3+2] = d2v*inv;
    }
    #pragma unroll
    for (int c=0;c<D;c++){
      float vv = y[c]*gm[c] + bt[c];
      out[p*D+c] = s[c] + lrelu(vv);
    }
  }
}

extern "C" void kernel_launch(void* const* d_in, const int* in_sizes, int n_in,
                              void* d_out, int out_size, void* d_ws, size_t ws_size,
                              hipStream_t stream){
  const float* xyz       = (const float*)d_in[0];
  const float* atom_xyz  = (const float*)d_in[1];
  const float* atomtypes = (const float*)d_in[2];
  const float* tt_w1 = (const float*)d_in[5];
  const float* tt_b1 = (const float*)d_in[6];
  const float* tt_w2 = (const float*)d_in[7];
  const float* tt_b2 = (const float*)d_in[8];
  const float* aa_w1 = (const float*)d_in[9];
  const float* aa_b1 = (const float*)d_in[10];
  const float* aa_w2 = (const float*)d_in[11];
  const float* aa_b2 = (const float*)d_in[12];
  const float* aa_gamma = (const float*)d_in[13];
  const float* aa_beta  = (const float*)d_in[14];
  const float* em_w1 = (const float*)d_in[15];
  const float* em_b1 = (const float*)d_in[16];
  const float* em_w2 = (const float*)d_in[17];
  const float* em_b2 = (const float*)d_in[18];
  const float* em_gamma = (const float*)d_in[19];
  const float* em_beta  = (const float*)d_in[20];

  const int n_pts = in_sizes[0]/3;
  const int n_at  = in_sizes[1]/3;

  char* ws = (char*)d_ws;
  float4* candP = (float4*)ws; ws += (size_t)MPAD*sizeof(float4);
  float4* ptsP  = (float4*)ws; ws += (size_t)n_pts*sizeof(float4);
  float* fa   = (float*)ws; ws += (size_t)n_at*D*4;
  float* fb   = (float*)ws; ws += (size_t)n_at*D*4;
  int*   idxA = (int*)ws;   ws += (size_t)n_at*KOUT*4;
  float* distA= (float*)ws; ws += (size_t)n_at*KOUT*4;
  int*   idxP = (int*)ws;   ws += (size_t)n_pts*KOUT*4;
  float* distP= (float*)ws; ws += (size_t)n_pts*KOUT*4;
  float* ea   = (float*)ws; ws += (size_t)n_pts*D*4;
  float* eb   = (float*)ws; ws += (size_t)n_pts*D*4;
  float* outf = (float*)d_out;

  const int nprep = (MPAD > n_pts ? MPAD : n_pts);
  prep_kernel<<<(nprep+255)/256,256,0,stream>>>(
      atom_xyz, xyz, atomtypes, tt_w1, tt_b1, tt_w2, tt_b2,
      candP, ptsP, fa, n_at, n_pts);

  // ---- fused KNN: blocks [0,nbA) = atom-atom k=17 drop-self;
  //                 blocks [nbA,nbA+nbB) = point-atom k=16 ----
  const int nbA = (n_at  + QBLK - 1) / QBLK;
  const int nbB = (n_pts + QBLK - 1) / QBLK;
  knn10_kernel<<<nbA + nbB,256,0,stream>>>(
      candP, n_at, candP, n_at, nbA, ptsP, n_pts,
      idxA, distA, idxP, distP);

  mp_kernel<false><<<(n_at*4+255)/256,256,0,stream>>>(fa, fa, idxA, distA,
      aa_w1+0*H*H, aa_b1+0*H, aa_w2+0*D*H, aa_b2+0*D, aa_gamma+0*D, aa_beta+0*D, fb, n_at);
  mp_kernel<false><<<(n_at*4+255)/256,256,0,stream>>>(fb, fb, idxA, distA,
      aa_w1+1*H*H, aa_b1+1*H, aa_w2+1*D*H, aa_b2+1*D, aa_gamma+1*D, aa_beta+1*D, fa, n_at);
  mp_kernel<false><<<(n_at*4+255)/256,256,0,stream>>>(fa, fa, idxA, distA,
      aa_w1+2*H*H, aa_b1+2*H, aa_w2+2*D*H, aa_b2+2*D, aa_gamma+2*D, aa_beta+2*D, fb, n_at);
  // final atom features in fb

  mp_kernel<true ><<<(n_pts*4+255)/256,256,0,stream>>>(nullptr, fb, idxP, distP,
      em_w1+0*H*H, em_b1+0*H, em_w2+0*D*H, em_b2+0*D, em_gamma+0*D, em_beta+0*D, ea, n_pts);
  mp_kernel<false><<<(n_pts*4+255)/256,256,0,stream>>>(ea, fb, idxP, distP,
      em_w1+1*H*H, em_b1+1*H, em_w2+1*D*H, em_b2+1*D, em_gamma+1*D, em_beta+1*D, eb, n_pts);
  mp_kernel<false><<<(n_pts*4+255)/256,256,0,stream>>>(eb, fb, idxP, distP,
      em_w1+2*H*H, em_b1+2*H, em_w2+2*D*H, em_b2+2*D, em_gamma+2*D, em_beta+2*D, outf, n_pts);
}

// Round 16
// 176.476 us; speedup vs baseline: 1.0163x; 1.0163x over previous
//
#include <hip/hip_runtime.h>
#include <cfloat>
#include <climits>

#define NEG 0.2f
#define GEPS 1e-5f
#define D 6
#define H 13   // 2*D+1
#define KOUT 16

#define MPAD 8192      // padded candidate capacity (NTILES*TILE)
#define TILE 1024      // candidates per LDS tile (16 KB)
#define NTILES 8       // MPAD / TILE
#define QW 8           // queries per wave
#define QBLK 32        // queries per block (4 waves)
#define CAP 64         // survivor slots per query
#define KMAX 17        // max KSEL (atom task)
#define MARGIN 0.05f   // e-space margin covering fma-vs-reference rounding

__device__ __forceinline__ float lrelu(float x){ return x >= 0.f ? x : NEG*x; }

// fused prep: pack atoms (padded) + pack points + atomtype MLP
__global__ void prep_kernel(const float* __restrict__ atom_xyz,
                            const float* __restrict__ xyz,
                            const float* __restrict__ at_in,
                            const float* __restrict__ w1, const float* __restrict__ b1,
                            const float* __restrict__ w2, const float* __restrict__ b2,
                            float4* __restrict__ candP, float4* __restrict__ ptsP,
                            float* __restrict__ fa, int n_at, int n_pts){
  int i = blockIdx.x*blockDim.x + threadIdx.x;
  if (i < MPAD){
    if (i < n_at){
      float x = atom_xyz[3*i], y = atom_xyz[3*i+1], z = atom_xyz[3*i+2];
      float sq;
      {
#pragma clang fp contract(off)
        sq = (x*x + y*y) + z*z;
      }
      candP[i] = make_float4(x,y,z,sq);
    } else {
      candP[i] = make_float4(0.f,0.f,0.f,1e30f); // never a min/survivor
    }
  }
  if (i < n_pts){
    float x = xyz[3*i], y = xyz[3*i+1], z = xyz[3*i+2];
    float sq;
    {
#pragma clang fp contract(off)
      sq = (x*x + y*y) + z*z;
    }
    ptsP[i] = make_float4(x,y,z,sq);
  }
  if (i < n_at){
    float x[D], h[D];
    #pragma unroll
    for (int j=0;j<D;j++) x[j] = at_in[i*D+j];
    #pragma unroll
    for (int o=0;o<D;o++){
      float acc = b1[o];
      #pragma unroll
      for (int j=0;j<D;j++) acc += w1[o*D+j]*x[j];
      h[o] = lrelu(acc);
    }
    #pragma unroll
    for (int o=0;o<D;o++){
      float acc = b2[o];
      #pragma unroll
      for (int j=0;j<D;j++) acc += w2[o*D+j]*h[j];
      fa[i*D+o] = acc;
    }
  }
}

// QW independent ascending value-sorts across 64 lanes (ILP-batched)
__device__ __forceinline__ void sort64fq(float (&v)[QW], int lane){
  #pragma unroll
  for (int k = 2; k <= 64; k <<= 1){
    #pragma unroll
    for (int j = k >> 1; j >= 1; j >>= 1){
      bool dir = ((lane & j) == 0) == ((lane & k) == 0);
      #pragma unroll
      for (int q = 0; q < QW; ++q){
        float o = __shfl_xor(v[q], j);
        v[q] = dir ? fminf(v[q], o) : fmaxf(v[q], o);
      }
    }
  }
}

// ascending lexicographic (d, i) bitonic sort across 64 lanes
__device__ __forceinline__ void sort64pair(float& d, int& i, int lane){
  #pragma unroll
  for (int k = 2; k <= 64; k <<= 1){
    #pragma unroll
    for (int j = k >> 1; j >= 1; j >>= 1){
      float od = __shfl_xor(d, j);
      int   oi = __shfl_xor(i, j);
      bool lower = (lane & j) == 0;
      bool asc   = (lane & k) == 0;
      bool oless = (od < d) || (od == d && oi < i);
      bool take  = (lower == asc) ? oless : !oless;
      d = take ? od : d;
      i = take ? oi : i;
    }
  }
}

// KNN v11: R14's fused LDS-tiled two-pass selection (QW=8, full pass-1
// threshold — proven) + register-staged DOUBLE-BUFFERED tiles: next tile's
// global loads are issued into registers BEFORE computing the current tile
// (latency hides under ~1024 cyc of VALU), regs->LDS write + ONE barrier per
// tile. Selection machinery identical to R14: T(q) = ksel-th smallest of 64
// per-lane e-mins (64 disjoint witnesses) + MARGIN; survivors -> LDS slots
// via rare-path atomicAdd (unordered); exact contract-off lex (d2,idx) sort;
// serial exact fallback on (astronomically rare, never observed) overflow.
__global__ __launch_bounds__(256)
void knn11_kernel(const float4* __restrict__ candP, int ncand,
                  const float4* __restrict__ qarrA, int nqA, int nbA,
                  const float4* __restrict__ qarrB, int nqB,
                  int* __restrict__ oidxA, float* __restrict__ odistA,
                  int* __restrict__ oidxB, float* __restrict__ odistB){
  __shared__ float4 tile[2][TILE];         // 32 KB (double buffer)
  __shared__ float4 qs[QBLK];
  __shared__ ushort slots[4][QW][CAP];     // 4 KB
  __shared__ int    scnt[4][QW];

  const int tid  = threadIdx.x;
  const int w    = tid >> 6;
  const int lane = tid & 63;

  const bool taskA = (int)blockIdx.x < nbA;
  const int  bq    = taskA ? blockIdx.x : (blockIdx.x - nbA);
  const float4* __restrict__ qarr = taskA ? qarrA : qarrB;
  const int  nq    = taskA ? nqA : nqB;
  const int  ksel  = taskA ? 17 : 16;
  const int  ooff  = taskA ? 1  : 0;
  int*   __restrict__ oidx  = taskA ? oidxA  : oidxB;
  float* __restrict__ odist = taskA ? odistA : odistB;

  if (tid < QBLK){
    int qg = bq*QBLK + tid;
    qs[tid] = qarr[qg < nq ? qg : nq-1];   // clamp: all waves stay full
  }
  if (lane < QW) scnt[w][lane] = 0;

  // -2*q in registers (e = fma(q2x,cx, fma(q2y,cy, fma(q2z,cz, cw))))
  // (qs read below is guarded by the prologue barrier)
  float4 st[4];
  #pragma unroll
  for (int u = 0; u < 4; ++u) st[u] = candP[tid + 256*u];  // tile 0
  #pragma unroll
  for (int u = 0; u < 4; ++u) tile[0][tid + 256*u] = st[u];
  __syncthreads();

  float q2x[QW], q2y[QW], q2z[QW];
  #pragma unroll
  for (int q = 0; q < QW; ++q){
    float4 v = qs[w*QW + q];
    q2x[q] = -2.f*v.x; q2y[q] = -2.f*v.y; q2z[q] = -2.f*v.z;
  }

  // ------- pass 1: per-lane e-min per query (double-buffered tiles) ------
  float mn[QW];
  #pragma unroll
  for (int q = 0; q < QW; ++q) mn[q] = FLT_MAX;

  for (int t = 0; t < NTILES; ++t){
    const int cur = t & 1;
    if (t+1 < NTILES){
      #pragma unroll
      for (int u = 0; u < 4; ++u) st[u] = candP[(t+1)*TILE + tid + 256*u];
    }
    #pragma unroll 2
    for (int i = 0; i < TILE/64; ++i){
      float4 cv = tile[cur][i*64 + lane];
      #pragma unroll
      for (int q = 0; q < QW; ++q){
        float e = fmaf(q2x[q], cv.x, fmaf(q2y[q], cv.y, fmaf(q2z[q], cv.z, cv.w)));
        mn[q] = fminf(mn[q], e);
      }
    }
    if (t+1 < NTILES){
      #pragma unroll
      for (int u = 0; u < 4; ++u) tile[cur^1][tid + 256*u] = st[u];
    }
    __syncthreads();
  }

  // threshold per query: ksel-th smallest lane-min + margin
  sort64fq(mn, lane);
  float T[QW];
  #pragma unroll
  for (int q = 0; q < QW; ++q) T[q] = __shfl(mn[q], ksel-1) + MARGIN;

  // ------- pass 2: collect survivors (double-buffered tiles) -------------
  #pragma unroll
  for (int u = 0; u < 4; ++u) st[u] = candP[tid + 256*u];  // tile 0 again
  #pragma unroll
  for (int u = 0; u < 4; ++u) tile[0][tid + 256*u] = st[u];
  __syncthreads();

  for (int t = 0; t < NTILES; ++t){
    const int cur = t & 1;
    if (t+1 < NTILES){
      #pragma unroll
      for (int u = 0; u < 4; ++u) st[u] = candP[(t+1)*TILE + tid + 256*u];
    }
    #pragma unroll 2
    for (int i = 0; i < TILE/64; ++i){
      float4 cv = tile[cur][i*64 + lane];
      const int j = t*TILE + i*64 + lane;
      #pragma unroll
      for (int q = 0; q < QW; ++q){
        float e = fmaf(q2x[q], cv.x, fmaf(q2y[q], cv.y, fmaf(q2z[q], cv.z, cv.w)));
        if (e <= T[q]){
          int ofs = atomicAdd(&scnt[w][q], 1);
          if (ofs < CAP) slots[w][q][ofs] = (ushort)j;
        }
      }
    }
    if (t+1 < NTILES){
      #pragma unroll
      for (int u = 0; u < 4; ++u) tile[cur^1][tid + 256*u] = st[u];
    }
    __syncthreads();
  }

  // ---------------- phase 3: exact per-query select ----------------
  for (int q = 0; q < QW; ++q){
    const int qgq = bq*QBLK + w*QW + q;
    if (qgq >= nq) continue;                 // wave-uniform
    const float4 qv = qs[w*QW + q];
    const int C = scnt[w][q];

    if (C <= CAP){
      int g = INT_MAX; float d2 = FLT_MAX;
      if (lane < C){
        g = slots[w][q][lane];
        float4 cp = candP[g];
        {
#pragma clang fp contract(off)
          float dot = qv.x*cp.x + qv.y*cp.y + qv.z*cp.z;
          d2 = (qv.w + cp.w) - 2.0f*dot;
        }
      }
      sort64pair(d2, g, lane);
      if (lane >= ooff && lane < ooff + KOUT){
        float4 cp = candP[g];
        float dist;
        {
#pragma clang fp contract(off)
          float dx = qv.x-cp.x, dy = qv.y-cp.y, dz = qv.z-cp.z;
          dist = (dx*dx + dy*dy) + dz*dz;
        }
        oidx[(size_t)qgq*KOUT + (lane-ooff)]  = g;
        odist[(size_t)qgq*KOUT + (lane-ooff)] = dist;
      }
    } else if (lane == 0){
      // astronomically rare slot overflow: serial exact full scan
      float bd[KMAX]; int bi[KMAX];
      for (int t=0;t<ksel;t++){ bd[t]=FLT_MAX; bi[t]=INT_MAX; }
      float cmd = FLT_MAX; int cmi = INT_MAX;
      for (int jj = 0; jj < ncand; ++jj){
        float4 cp = candP[jj];
        float d2;
        {
#pragma clang fp contract(off)
          float dot = qv.x*cp.x + qv.y*cp.y + qv.z*cp.z;
          d2 = (qv.w + cp.w) - 2.0f*dot;
        }
        if (d2 < cmd || (d2 == cmd && jj < cmi)){
          int rt = 0; float rmd=-FLT_MAX; int rmi=-1;
          for (int t=0;t<ksel;t++){
            if (bd[t] > rmd || (bd[t]==rmd && bi[t]>rmi)){ rmd=bd[t]; rmi=bi[t]; rt=t; }
          }
          bd[rt]=d2; bi[rt]=jj;
          cmd=-FLT_MAX; cmi=-1;
          for (int t=0;t<ksel;t++){
            if (bd[t] > cmd || (bd[t]==cmd && bi[t]>cmi)){ cmd=bd[t]; cmi=bi[t]; }
          }
        }
      }
      for (int t=0;t<ksel;t++){
        int rt=-1; float mnd=FLT_MAX; int mni=INT_MAX;
        for (int u2=0;u2<ksel;u2++){
          if (bd[u2] < mnd || (bd[u2]==mnd && bi[u2]<mni)){ mnd=bd[u2]; mni=bi[u2]; rt=u2; }
        }
        bd[rt]=FLT_MAX; bi[rt]=INT_MAX;
        if (t >= ooff){
          float4 cp = candP[mni];
          float dist;
          {
#pragma clang fp contract(off)
            float dx=qv.x-cp.x, dy=qv.y-cp.y, dz=qv.z-cp.z;
            dist = (dx*dx + dy*dy) + dz*dz;
          }
          oidx[(size_t)qgq*KOUT + (t-ooff)]  = mni;
          odist[(size_t)qgq*KOUT + (t-ooff)] = dist;
        }
      }
    }
  }
}

// One message-passing block: out = self + lrelu(groupnorm(sum_k MLP(feat_k)))
// 4 threads per point: each handles 4 of the 16 neighbors, shfl-reduce.
template<bool SELF_ONES>
__global__ __launch_bounds__(256)
void mp_kernel(const float* __restrict__ self_feat,
               const float* __restrict__ nb_src,
               const int* __restrict__ idx,
               const float* __restrict__ dists,
               const float* __restrict__ w1g, const float* __restrict__ b1g,
               const float* __restrict__ w2g, const float* __restrict__ b2g,
               const float* __restrict__ gam, const float* __restrict__ bet,
               float* __restrict__ out, int n){
  __shared__ float w1[H*H], b1v[H], w2[D*H], b2v[D], gm[D], bt[D];
  for (int t=threadIdx.x; t<H*H; t+=blockDim.x) w1[t]=w1g[t];
  if (threadIdx.x < H) b1v[threadIdx.x]=b1g[threadIdx.x];
  for (int t=threadIdx.x; t<D*H; t+=blockDim.x) w2[t]=w2g[t];
  if (threadIdx.x < D){
    b2v[threadIdx.x]=b2g[threadIdx.x];
    gm[threadIdx.x]=gam[threadIdx.x];
    bt[threadIdx.x]=bet[threadIdx.x];
  }
  __syncthreads();
  int tt = blockIdx.x*blockDim.x + threadIdx.x;
  int p = tt >> 2, sub = tt & 3;
  if (p >= n) return;

  float s[D];
  #pragma unroll
  for (int j=0;j<D;j++) s[j] = SELF_ONES ? 1.0f : self_feat[p*D+j];
  float msg[D] = {0,0,0,0,0,0};

  #pragma unroll
  for (int u=0;u<KOUT/4;u++){
    int k = u*4 + sub;
    int j = idx[p*KOUT+k];
    float dd = dists[p*KOUT+k];
    float f[H];
    #pragma unroll
    for (int c=0;c<D;c++) f[c]=s[c];
    #pragma unroll
    for (int c=0;c<D;c++) f[D+c]=nb_src[j*D+c];
    f[2*D]=dd;
    float h[H];
    #pragma unroll
    for (int o=0;o<H;o++){
      float acc=b1v[o];
      #pragma unroll
      for (int c=0;c<H;c++) acc += w1[o*H+c]*f[c];
      h[o]=lrelu(acc);
    }
    #pragma unroll
    for (int o=0;o<D;o++){
      float acc=b2v[o];
      #pragma unroll
      for (int c=0;c<H;c++) acc += w2[o*H+c]*h[c];
      msg[o]+=acc;
    }
  }

  #pragma unroll
  for (int c=0;c<D;c++){
    msg[c] += __shfl_xor(msg[c], 1);
    msg[c] += __shfl_xor(msg[c], 2);
  }

  if (sub == 0){
    float y[D];
    #pragma unroll
    for (int gi=0; gi<2; gi++){
      float m0=msg[gi*3+0], m1=msg[gi*3+1], m2=msg[gi*3+2];
      float mu = ((m0+m1)+m2) / 3.0f;
      float d0=m0-mu, d1=m1-mu, d2v=m2-mu;
      float var = ((d0*d0 + d1*d1) + d2v*d2v) / 3.0f;
      float inv = 1.0f / sqrtf(var + GEPS);
      y[gi*3+0] = d0*inv;
      y[gi*3+1] = d1*inv;
      y[gi*3+2] = d2v*inv;
    }
    #pragma unroll
    for (int c=0;c<D;c++){
      float vv = y[c]*gm[c] + bt[c];
      out[p*D+c] = s[c] + lrelu(vv);
    }
  }
}

extern "C" void kernel_launch(void* const* d_in, const int* in_sizes, int n_in,
                              void* d_out, int out_size, void* d_ws, size_t ws_size,
                              hipStream_t stream){
  const float* xyz       = (const float*)d_in[0];
  const float* atom_xyz  = (const float*)d_in[1];
  const float* atomtypes = (const float*)d_in[2];
  const float* tt_w1 = (const float*)d_in[5];
  const float* tt_b1 = (const float*)d_in[6];
  const float* tt_w2 = (const float*)d_in[7];
  const float* tt_b2 = (const float*)d_in[8];
  const float* aa_w1 = (const float*)d_in[9];
  const float* aa_b1 = (const float*)d_in[10];
  const float* aa_w2 = (const float*)d_in[11];
  const float* aa_b2 = (const float*)d_in[12];
  const float* aa_gamma = (const float*)d_in[13];
  const float* aa_beta  = (const float*)d_in[14];
  const float* em_w1 = (const float*)d_in[15];
  const float* em_b1 = (const float*)d_in[16];
  const float* em_w2 = (const float*)d_in[17];
  const float* em_b2 = (const float*)d_in[18];
  const float* em_gamma = (const float*)d_in[19];
  const float* em_beta  = (const float*)d_in[20];

  const int n_pts = in_sizes[0]/3;
  const int n_at  = in_sizes[1]/3;

  char* ws = (char*)d_ws;
  float4* candP = (float4*)ws; ws += (size_t)MPAD*sizeof(float4);
  float4* ptsP  = (float4*)ws; ws += (size_t)n_pts*sizeof(float4);
  float* fa   = (float*)ws; ws += (size_t)n_at*D*4;
  float* fb   = (float*)ws; ws += (size_t)n_at*D*4;
  int*   idxA = (int*)ws;   ws += (size_t)n_at*KOUT*4;
  float* distA= (float*)ws; ws += (size_t)n_at*KOUT*4;
  int*   idxP = (int*)ws;   ws += (size_t)n_pts*KOUT*4;
  float* distP= (float*)ws; ws += (size_t)n_pts*KOUT*4;
  float* ea   = (float*)ws; ws += (size_t)n_pts*D*4;
  float* eb   = (float*)ws; ws += (size_t)n_pts*D*4;
  float* outf = (float*)d_out;

  const int nprep = (MPAD > n_pts ? MPAD : n_pts);
  prep_kernel<<<(nprep+255)/256,256,0,stream>>>(
      atom_xyz, xyz, atomtypes, tt_w1, tt_b1, tt_w2, tt_b2,
      candP, ptsP, fa, n_at, n_pts);

  // ---- fused KNN: blocks [0,nbA) = atom-atom k=17 drop-self;
  //                 blocks [nbA,nbA+nbB) = point-atom k=16 ----
  const int nbA = (n_at  + QBLK - 1) / QBLK;
  const int nbB = (n_pts + QBLK - 1) / QBLK;
  knn11_kernel<<<nbA + nbB,256,0,stream>>>(
      candP, n_at, candP, n_at, nbA, ptsP, n_pts,
      idxA, distA, idxP, distP);

  mp_kernel<false><<<(n_at*4+255)/256,256,0,stream>>>(fa, fa, idxA, distA,
      aa_w1+0*H*H, aa_b1+0*H, aa_w2+0*D*H, aa_b2+0*D, aa_gamma+0*D, aa_beta+0*D, fb, n_at);
  mp_kernel<false><<<(n_at*4+255)/256,256,0,stream>>>(fb, fb, idxA, distA,
      aa_w1+1*H*H, aa_b1+1*H, aa_w2+1*D*H, aa_b2+1*D, aa_gamma+1*D, aa_beta+1*D, fa, n_at);
  mp_kernel<false><<<(n_at*4+255)/256,256,0,stream>>>(fa, fa, idxA, distA,
      aa_w1+2*H*H, aa_b1+2*H, aa_w2+2*D*H, aa_b2+2*D, aa_gamma+2*D, aa_beta+2*D, fb, n_at);
  // final atom features in fb

  mp_kernel<true ><<<(n_pts*4+255)/256,256,0,stream>>>(nullptr, fb, idxP, distP,
      em_w1+0*H*H, em_b1+0*H, em_w2+0*D*H, em_b2+0*D, em_gamma+0*D, em_beta+0*D, ea, n_pts);
  mp_kernel<false><<<(n_pts*4+255)/256,256,0,stream>>>(ea, fb, idxP, distP,
      em_w1+1*H*H, em_b1+1*H, em_w2+1*D*H, em_b2+1*D, em_gamma+1*D, em_beta+1*D, eb, n_pts);
  mp_kernel<false><<<(n_pts*4+255)/256,256,0,stream>>>(eb, fb, idxP, distP,
      em_w1+2*H*H, em_b1+2*H, em_w2+2*D*H, em_b2+2*D, em_gamma+2*D, em_beta+2*D, outf, n_pts);
}

// Round 17
// 158.662 us; speedup vs baseline: 1.1304x; 1.1123x over previous
//
#include <hip/hip_runtime.h>
#include <cfloat>
#include <climits>

#define NEG 0.2f
#define GEPS 1e-5f
#define D 6
#define H 13   // 2*D+1
#define KOUT 16

#define MPAD 8192      // padded candidate capacity (NTILES*TILE)
#define TILE 1024      // candidates per LDS tile (16 KB)
#define NTILES 8       // MPAD / TILE
#define QW 8           // queries per wave
#define QBLK 32        // queries per block (4 waves)
#define CAP 64         // survivor slots per query
#define KMAX 17        // max KSEL (atom task)
#define MARGIN 0.05f   // e-space margin covering fma-vs-reference rounding

__device__ __forceinline__ float lrelu(float x){ return x >= 0.f ? x : NEG*x; }

// fused prep: pack atoms (padded) + pack points + atomtype MLP
__global__ void prep_kernel(const float* __restrict__ atom_xyz,
                            const float* __restrict__ xyz,
                            const float* __restrict__ at_in,
                            const float* __restrict__ w1, const float* __restrict__ b1,
                            const float* __restrict__ w2, const float* __restrict__ b2,
                            float4* __restrict__ candP, float4* __restrict__ ptsP,
                            float* __restrict__ fa, int n_at, int n_pts){
  int i = blockIdx.x*blockDim.x + threadIdx.x;
  if (i < MPAD){
    if (i < n_at){
      float x = atom_xyz[3*i], y = atom_xyz[3*i+1], z = atom_xyz[3*i+2];
      float sq;
      {
#pragma clang fp contract(off)
        sq = (x*x + y*y) + z*z;
      }
      candP[i] = make_float4(x,y,z,sq);
    } else {
      candP[i] = make_float4(0.f,0.f,0.f,1e30f); // never a min/survivor
    }
  }
  if (i < n_pts){
    float x = xyz[3*i], y = xyz[3*i+1], z = xyz[3*i+2];
    float sq;
    {
#pragma clang fp contract(off)
      sq = (x*x + y*y) + z*z;
    }
    ptsP[i] = make_float4(x,y,z,sq);
  }
  if (i < n_at){
    float x[D], h[D];
    #pragma unroll
    for (int j=0;j<D;j++) x[j] = at_in[i*D+j];
    #pragma unroll
    for (int o=0;o<D;o++){
      float acc = b1[o];
      #pragma unroll
      for (int j=0;j<D;j++) acc += w1[o*D+j]*x[j];
      h[o] = lrelu(acc);
    }
    #pragma unroll
    for (int o=0;o<D;o++){
      float acc = b2[o];
      #pragma unroll
      for (int j=0;j<D;j++) acc += w2[o*D+j]*h[j];
      fa[i*D+o] = acc;
    }
  }
}

// QW independent ascending value-sorts across 64 lanes (ILP-batched)
__device__ __forceinline__ void sort64fq(float (&v)[QW], int lane){
  #pragma unroll
  for (int k = 2; k <= 64; k <<= 1){
    #pragma unroll
    for (int j = k >> 1; j >= 1; j >>= 1){
      bool dir = ((lane & j) == 0) == ((lane & k) == 0);
      #pragma unroll
      for (int q = 0; q < QW; ++q){
        float o = __shfl_xor(v[q], j);
        v[q] = dir ? fminf(v[q], o) : fmaxf(v[q], o);
      }
    }
  }
}

// ascending lexicographic (d, i) bitonic sort across 64 lanes
__device__ __forceinline__ void sort64pair(float& d, int& i, int lane){
  #pragma unroll
  for (int k = 2; k <= 64; k <<= 1){
    #pragma unroll
    for (int j = k >> 1; j >= 1; j >>= 1){
      float od = __shfl_xor(d, j);
      int   oi = __shfl_xor(i, j);
      bool lower = (lane & j) == 0;
      bool asc   = (lane & k) == 0;
      bool oless = (od < d) || (od == d && oi < i);
      bool take  = (lower == asc) ? oless : !oless;
      d = take ? od : d;
      i = take ? oi : i;
    }
  }
}

// KNN v9 (R14, proven 107 us): LDS-tiled two-pass selection with QW=8
// (VALU:LDS pipe ~16:12 per CU per iter) and BOTH tasks (atom k=17
// drop-self, point k=16) fused into one dispatch via block-range task
// selection (875 blocks). T(q) = ksel-th smallest of 64 per-lane e-mins
// (64 disjoint witnesses) + MARGIN; survivors -> LDS slots via rare-path
// atomicAdd (unordered); exact contract-off lex (d2,idx) sort across lanes;
// serial exact fallback on (astronomically rare) slot overflow.
__global__ __launch_bounds__(256)
void knn9_kernel(const float4* __restrict__ candP, int ncand,
                 const float4* __restrict__ qarrA, int nqA, int nbA,
                 const float4* __restrict__ qarrB, int nqB,
                 int* __restrict__ oidxA, float* __restrict__ odistA,
                 int* __restrict__ oidxB, float* __restrict__ odistB){
  __shared__ float4 tile[TILE];            // 16 KB
  __shared__ float4 qs[QBLK];
  __shared__ ushort slots[4][QW][CAP];     // 4 KB
  __shared__ int    scnt[4][QW];

  const int tid  = threadIdx.x;
  const int w    = tid >> 6;
  const int lane = tid & 63;

  const bool taskA = (int)blockIdx.x < nbA;
  const int  bq    = taskA ? blockIdx.x : (blockIdx.x - nbA);
  const float4* __restrict__ qarr = taskA ? qarrA : qarrB;
  const int  nq    = taskA ? nqA : nqB;
  const int  ksel  = taskA ? 17 : 16;
  const int  ooff  = taskA ? 1  : 0;
  int*   __restrict__ oidx  = taskA ? oidxA  : oidxB;
  float* __restrict__ odist = taskA ? odistA : odistB;

  if (tid < QBLK){
    int qg = bq*QBLK + tid;
    qs[tid] = qarr[qg < nq ? qg : nq-1];   // clamp: all waves stay full
  }
  if (lane < QW) scnt[w][lane] = 0;
  __syncthreads();

  // -2*q in registers (e = fma(q2x,cx, fma(q2y,cy, fma(q2z,cz, cw))))
  float q2x[QW], q2y[QW], q2z[QW];
  #pragma unroll
  for (int q = 0; q < QW; ++q){
    float4 v = qs[w*QW + q];
    q2x[q] = -2.f*v.x; q2y[q] = -2.f*v.y; q2z[q] = -2.f*v.z;
  }

  // ---------------- pass 1: per-lane e-min per query (LDS-tiled) ---------
  float mn[QW];
  #pragma unroll
  for (int q = 0; q < QW; ++q) mn[q] = FLT_MAX;

  for (int t = 0; t < NTILES; ++t){
    #pragma unroll
    for (int u = 0; u < TILE/256; ++u)
      tile[tid + 256*u] = candP[t*TILE + tid + 256*u];
    __syncthreads();
    #pragma unroll 2
    for (int i = 0; i < TILE/64; ++i){
      float4 cv = tile[i*64 + lane];
      #pragma unroll
      for (int q = 0; q < QW; ++q){
        float e = fmaf(q2x[q], cv.x, fmaf(q2y[q], cv.y, fmaf(q2z[q], cv.z, cv.w)));
        mn[q] = fminf(mn[q], e);
      }
    }
    __syncthreads();
  }

  // threshold per query: ksel-th smallest lane-min + margin
  sort64fq(mn, lane);
  float T[QW];
  #pragma unroll
  for (int q = 0; q < QW; ++q) T[q] = __shfl(mn[q], ksel-1) + MARGIN;

  // ---------------- pass 2: collect survivors (LDS-tiled) ----------------
  for (int t = 0; t < NTILES; ++t){
    #pragma unroll
    for (int u = 0; u < TILE/256; ++u)
      tile[tid + 256*u] = candP[t*TILE + tid + 256*u];
    __syncthreads();
    #pragma unroll 2
    for (int i = 0; i < TILE/64; ++i){
      float4 cv = tile[i*64 + lane];
      const int j = t*TILE + i*64 + lane;
      #pragma unroll
      for (int q = 0; q < QW; ++q){
        float e = fmaf(q2x[q], cv.x, fmaf(q2y[q], cv.y, fmaf(q2z[q], cv.z, cv.w)));
        if (e <= T[q]){
          int ofs = atomicAdd(&scnt[w][q], 1);
          if (ofs < CAP) slots[w][q][ofs] = (ushort)j;
        }
      }
    }
    __syncthreads();
  }

  // ---------------- phase 3: exact per-query select ----------------
  for (int q = 0; q < QW; ++q){
    const int qgq = bq*QBLK + w*QW + q;
    if (qgq >= nq) continue;                 // wave-uniform
    const float4 qv = qs[w*QW + q];
    const int C = scnt[w][q];

    if (C <= CAP){
      int g = INT_MAX; float d2 = FLT_MAX;
      if (lane < C){
        g = slots[w][q][lane];
        float4 cp = candP[g];
        {
#pragma clang fp contract(off)
          float dot = qv.x*cp.x + qv.y*cp.y + qv.z*cp.z;
          d2 = (qv.w + cp.w) - 2.0f*dot;
        }
      }
      sort64pair(d2, g, lane);
      if (lane >= ooff && lane < ooff + KOUT){
        float4 cp = candP[g];
        float dist;
        {
#pragma clang fp contract(off)
          float dx = qv.x-cp.x, dy = qv.y-cp.y, dz = qv.z-cp.z;
          dist = (dx*dx + dy*dy) + dz*dz;
        }
        oidx[(size_t)qgq*KOUT + (lane-ooff)]  = g;
        odist[(size_t)qgq*KOUT + (lane-ooff)] = dist;
      }
    } else if (lane == 0){
      // astronomically rare slot overflow: serial exact full scan
      float bd[KMAX]; int bi[KMAX];
      for (int t=0;t<ksel;t++){ bd[t]=FLT_MAX; bi[t]=INT_MAX; }
      float cmd = FLT_MAX; int cmi = INT_MAX;
      for (int jj = 0; jj < ncand; ++jj){
        float4 cp = candP[jj];
        float d2;
        {
#pragma clang fp contract(off)
          float dot = qv.x*cp.x + qv.y*cp.y + qv.z*cp.z;
          d2 = (qv.w + cp.w) - 2.0f*dot;
        }
        if (d2 < cmd || (d2 == cmd && jj < cmi)){
          int rt = 0; float rmd=-FLT_MAX; int rmi=-1;
          for (int t=0;t<ksel;t++){
            if (bd[t] > rmd || (bd[t]==rmd && bi[t]>rmi)){ rmd=bd[t]; rmi=bi[t]; rt=t; }
          }
          bd[rt]=d2; bi[rt]=jj;
          cmd=-FLT_MAX; cmi=-1;
          for (int t=0;t<ksel;t++){
            if (bd[t] > cmd || (bd[t]==cmd && bi[t]>cmi)){ cmd=bd[t]; cmi=bi[t]; }
          }
        }
      }
      for (int t=0;t<ksel;t++){
        int rt=-1; float mnd=FLT_MAX; int mni=INT_MAX;
        for (int u2=0;u2<ksel;u2++){
          if (bd[u2] < mnd || (bd[u2]==mnd && bi[u2]<mni)){ mnd=bd[u2]; mni=bi[u2]; rt=u2; }
        }
        bd[rt]=FLT_MAX; bi[rt]=INT_MAX;
        if (t >= ooff){
          float4 cp = candP[mni];
          float dist;
          {
#pragma clang fp contract(off)
            float dx=qv.x-cp.x, dy=qv.y-cp.y, dz=qv.z-cp.z;
            dist = (dx*dx + dy*dy) + dz*dz;
          }
          oidx[(size_t)qgq*KOUT + (t-ooff)]  = mni;
          odist[(size_t)qgq*KOUT + (t-ooff)] = dist;
        }
      }
    }
  }
}

// One message-passing block: out = self + lrelu(groupnorm(sum_k MLP(feat_k)))
// 4 threads per point: each handles 4 of the 16 neighbors, shfl-reduce.
template<bool SELF_ONES>
__global__ __launch_bounds__(256)
void mp_kernel(const float* __restrict__ self_feat,
               const float* __restrict__ nb_src,
               const int* __restrict__ idx,
               const float* __restrict__ dists,
               const float* __restrict__ w1g, const float* __restrict__ b1g,
               const float* __restrict__ w2g, const float* __restrict__ b2g,
               const float* __restrict__ gam, const float* __restrict__ bet,
               float* __restrict__ out, int n){
  __shared__ float w1[H*H], b1v[H], w2[D*H], b2v[D], gm[D], bt[D];
  for (int t=threadIdx.x; t<H*H; t+=blockDim.x) w1[t]=w1g[t];
  if (threadIdx.x < H) b1v[threadIdx.x]=b1g[threadIdx.x];
  for (int t=threadIdx.x; t<D*H; t+=blockDim.x) w2[t]=w2g[t];
  if (threadIdx.x < D){
    b2v[threadIdx.x]=b2g[threadIdx.x];
    gm[threadIdx.x]=gam[threadIdx.x];
    bt[threadIdx.x]=bet[threadIdx.x];
  }
  __syncthreads();
  int tt = blockIdx.x*blockDim.x + threadIdx.x;
  int p = tt >> 2, sub = tt & 3;
  if (p >= n) return;

  float s[D];
  #pragma unroll
  for (int j=0;j<D;j++) s[j] = SELF_ONES ? 1.0f : self_feat[p*D+j];
  float msg[D] = {0,0,0,0,0,0};

  #pragma unroll
  for (int u=0;u<KOUT/4;u++){
    int k = u*4 + sub;
    int j = idx[p*KOUT+k];
    float dd = dists[p*KOUT+k];
    float f[H];
    #pragma unroll
    for (int c=0;c<D;c++) f[c]=s[c];
    #pragma unroll
    for (int c=0;c<D;c++) f[D+c]=nb_src[j*D+c];
    f[2*D]=dd;
    float h[H];
    #pragma unroll
    for (int o=0;o<H;o++){
      float acc=b1v[o];
      #pragma unroll
      for (int c=0;c<H;c++) acc += w1[o*H+c]*f[c];
      h[o]=lrelu(acc);
    }
    #pragma unroll
    for (int o=0;o<D;o++){
      float acc=b2v[o];
      #pragma unroll
      for (int c=0;c<H;c++) acc += w2[o*H+c]*h[c];
      msg[o]+=acc;
    }
  }

  #pragma unroll
  for (int c=0;c<D;c++){
    msg[c] += __shfl_xor(msg[c], 1);
    msg[c] += __shfl_xor(msg[c], 2);
  }

  if (sub == 0){
    float y[D];
    #pragma unroll
    for (int gi=0; gi<2; gi++){
      float m0=msg[gi*3+0], m1=msg[gi*3+1], m2=msg[gi*3+2];
      float mu = ((m0+m1)+m2) / 3.0f;
      float d0=m0-mu, d1=m1-mu, d2v=m2-mu;
      float var = ((d0*d0 + d1*d1) + d2v*d2v) / 3.0f;
      float inv = 1.0f / sqrtf(var + GEPS);
      y[gi*3+0] = d0*inv;
      y[gi*3+1] = d1*inv;
      y[gi*3+2] = d2v*inv;
    }
    #pragma unroll
    for (int c=0;c<D;c++){
      float vv = y[c]*gm[c] + bt[c];
      out[p*D+c] = s[c] + lrelu(vv);
    }
  }
}

extern "C" void kernel_launch(void* const* d_in, const int* in_sizes, int n_in,
                              void* d_out, int out_size, void* d_ws, size_t ws_size,
                              hipStream_t stream){
  const float* xyz       = (const float*)d_in[0];
  const float* atom_xyz  = (const float*)d_in[1];
  const float* atomtypes = (const float*)d_in[2];
  const float* tt_w1 = (const float*)d_in[5];
  const float* tt_b1 = (const float*)d_in[6];
  const float* tt_w2 = (const float*)d_in[7];
  const float* tt_b2 = (const float*)d_in[8];
  const float* aa_w1 = (const float*)d_in[9];
  const float* aa_b1 = (const float*)d_in[10];
  const float* aa_w2 = (const float*)d_in[11];
  const float* aa_b2 = (const float*)d_in[12];
  const float* aa_gamma = (const float*)d_in[13];
  const float* aa_beta  = (const float*)d_in[14];
  const float* em_w1 = (const float*)d_in[15];
  const float* em_b1 = (const float*)d_in[16];
  const float* em_w2 = (const float*)d_in[17];
  const float* em_b2 = (const float*)d_in[18];
  const float* em_gamma = (const float*)d_in[19];
  const float* em_beta  = (const float*)d_in[20];

  const int n_pts = in_sizes[0]/3;
  const int n_at  = in_sizes[1]/3;

  char* ws = (char*)d_ws;
  float4* candP = (float4*)ws; ws += (size_t)MPAD*sizeof(float4);
  float4* ptsP  = (float4*)ws; ws += (size_t)n_pts*sizeof(float4);
  float* fa   = (float*)ws; ws += (size_t)n_at*D*4;
  float* fb   = (float*)ws; ws += (size_t)n_at*D*4;
  int*   idxA = (int*)ws;   ws += (size_t)n_at*KOUT*4;
  float* distA= (float*)ws; ws += (size_t)n_at*KOUT*4;
  int*   idxP = (int*)ws;   ws += (size_t)n_pts*KOUT*4;
  float* distP= (float*)ws; ws += (size_t)n_pts*KOUT*4;
  float* ea   = (float*)ws; ws += (size_t)n_pts*D*4;
  float* eb   = (float*)ws; ws += (size_t)n_pts*D*4;
  float* outf = (float*)d_out;

  const int nprep = (MPAD > n_pts ? MPAD : n_pts);
  prep_kernel<<<(nprep+255)/256,256,0,stream>>>(
      atom_xyz, xyz, atomtypes, tt_w1, tt_b1, tt_w2, tt_b2,
      candP, ptsP, fa, n_at, n_pts);

  // ---- fused KNN: blocks [0,nbA) = atom-atom k=17 drop-self;
  //                 blocks [nbA,nbA+nbB) = point-atom k=16 ----
  const int nbA = (n_at  + QBLK - 1) / QBLK;
  const int nbB = (n_pts + QBLK - 1) / QBLK;
  knn9_kernel<<<nbA + nbB,256,0,stream>>>(
      candP, n_at, candP, n_at, nbA, ptsP, n_pts,
      idxA, distA, idxP, distP);

  mp_kernel<false><<<(n_at*4+255)/256,256,0,stream>>>(fa, fa, idxA, distA,
      aa_w1+0*H*H, aa_b1+0*H, aa_w2+0*D*H, aa_b2+0*D, aa_gamma+0*D, aa_beta+0*D, fb, n_at);
  mp_kernel<false><<<(n_at*4+255)/256,256,0,stream>>>(fb, fb, idxA, distA,
      aa_w1+1*H*H, aa_b1+1*H, aa_w2+1*D*H, aa_b2+1*D, aa_gamma+1*D, aa_beta+1*D, fa, n_at);
  mp_kernel<false><<<(n_at*4+255)/256,256,0,stream>>>(fa, fa, idxA, distA,
      aa_w1+2*H*H, aa_b1+2*H, aa_w2+2*D*H, aa_b2+2*D, aa_gamma+2*D, aa_beta+2*D, fb, n_at);
  // final atom features in fb

  mp_kernel<true ><<<(n_pts*4+255)/256,256,0,stream>>>(nullptr, fb, idxP, distP,
      em_w1+0*H*H, em_b1+0*H, em_w2+0*D*H, em_b2+0*D, em_gamma+0*D, em_beta+0*D, ea, n_pts);
  mp_kernel<false><<<(n_pts*4+255)/256,256,0,stream>>>(ea, fb, idxP, distP,
      em_w1+1*H*H, em_b1+1*H, em_w2+1*D*H, em_b2+1*D, em_gamma+1*D, em_beta+1*D, eb, n_pts);
  mp_kernel<false><<<(n_pts*4+255)/256,256,0,stream>>>(eb, fb, idxP, distP,
      em_w1+2*H*H, em_b1+2*H, em_w2+2*D*H, em_b2+2*D, em_gamma+2*D, em_beta+2*D, outf, n_pts);
}

// Round 18
// 155.342 us; speedup vs baseline: 1.1545x; 1.0214x over previous
//
#include <hip/hip_runtime.h>
#include <cfloat>
#include <climits>

#define NEG 0.2f
#define GEPS 1e-5f
#define D 6
#define H 13   // 2*D+1
#define KOUT 16

#define MPAD 8192      // padded candidate capacity (NTILES*TILE)
#define TILE 2048      // candidates per LDS tile (32 KB)
#define NTILES 4       // MPAD / TILE
#define QW 8           // queries per wave
#define QBLK 32        // queries per block (4 waves)
#define CAP 64         // survivor slots per query
#define KMAX 17        // max KSEL (atom task)
#define MARGIN 0.05f   // e-space margin covering fma-vs-reference rounding

__device__ __forceinline__ float lrelu(float x){ return x >= 0.f ? x : NEG*x; }

// fused prep: pack atoms (padded) + pack points + atomtype MLP
__global__ void prep_kernel(const float* __restrict__ atom_xyz,
                            const float* __restrict__ xyz,
                            const float* __restrict__ at_in,
                            const float* __restrict__ w1, const float* __restrict__ b1,
                            const float* __restrict__ w2, const float* __restrict__ b2,
                            float4* __restrict__ candP, float4* __restrict__ ptsP,
                            float* __restrict__ fa, int n_at, int n_pts){
  int i = blockIdx.x*blockDim.x + threadIdx.x;
  if (i < MPAD){
    if (i < n_at){
      float x = atom_xyz[3*i], y = atom_xyz[3*i+1], z = atom_xyz[3*i+2];
      float sq;
      {
#pragma clang fp contract(off)
        sq = (x*x + y*y) + z*z;
      }
      candP[i] = make_float4(x,y,z,sq);
    } else {
      candP[i] = make_float4(0.f,0.f,0.f,1e30f); // never a min/survivor
    }
  }
  if (i < n_pts){
    float x = xyz[3*i], y = xyz[3*i+1], z = xyz[3*i+2];
    float sq;
    {
#pragma clang fp contract(off)
      sq = (x*x + y*y) + z*z;
    }
    ptsP[i] = make_float4(x,y,z,sq);
  }
  if (i < n_at){
    float x[D], h[D];
    #pragma unroll
    for (int j=0;j<D;j++) x[j] = at_in[i*D+j];
    #pragma unroll
    for (int o=0;o<D;o++){
      float acc = b1[o];
      #pragma unroll
      for (int j=0;j<D;j++) acc += w1[o*D+j]*x[j];
      h[o] = lrelu(acc);
    }
    #pragma unroll
    for (int o=0;o<D;o++){
      float acc = b2[o];
      #pragma unroll
      for (int j=0;j<D;j++) acc += w2[o*D+j]*h[j];
      fa[i*D+o] = acc;
    }
  }
}

// QW independent ascending value-sorts across 64 lanes (ILP-batched)
__device__ __forceinline__ void sort64fq(float (&v)[QW], int lane){
  #pragma unroll
  for (int k = 2; k <= 64; k <<= 1){
    #pragma unroll
    for (int j = k >> 1; j >= 1; j >>= 1){
      bool dir = ((lane & j) == 0) == ((lane & k) == 0);
      #pragma unroll
      for (int q = 0; q < QW; ++q){
        float o = __shfl_xor(v[q], j);
        v[q] = dir ? fminf(v[q], o) : fmaxf(v[q], o);
      }
    }
  }
}

// ascending lexicographic (d, i) bitonic sort across 64 lanes
__device__ __forceinline__ void sort64pair(float& d, int& i, int lane){
  #pragma unroll
  for (int k = 2; k <= 64; k <<= 1){
    #pragma unroll
    for (int j = k >> 1; j >= 1; j >>= 1){
      float od = __shfl_xor(d, j);
      int   oi = __shfl_xor(i, j);
      bool lower = (lane & j) == 0;
      bool asc   = (lane & k) == 0;
      bool oless = (od < d) || (od == d && oi < i);
      bool take  = (lower == asc) ? oless : !oless;
      d = take ? od : d;
      i = take ? oi : i;
    }
  }
}

// KNN v9b (R14 structure, TILE=2048): LDS-tiled two-pass selection, QW=8,
// both tasks fused via block-range selection. Fewer barriers (16 vs 32
// staging events) with 2x compute per stage. T(q) = ksel-th smallest of 64
// per-lane e-mins (64 disjoint witnesses) + MARGIN; survivors -> LDS slots
// via rare-path atomicAdd (unordered); exact contract-off lex (d2,idx) sort
// across lanes; serial exact fallback on (astronomically rare) overflow.
__global__ __launch_bounds__(256)
void knn9_kernel(const float4* __restrict__ candP, int ncand,
                 const float4* __restrict__ qarrA, int nqA, int nbA,
                 const float4* __restrict__ qarrB, int nqB,
                 int* __restrict__ oidxA, float* __restrict__ odistA,
                 int* __restrict__ oidxB, float* __restrict__ odistB){
  __shared__ float4 tile[TILE];            // 32 KB
  __shared__ float4 qs[QBLK];
  __shared__ ushort slots[4][QW][CAP];     // 4 KB
  __shared__ int    scnt[4][QW];

  const int tid  = threadIdx.x;
  const int w    = tid >> 6;
  const int lane = tid & 63;

  const bool taskA = (int)blockIdx.x < nbA;
  const int  bq    = taskA ? blockIdx.x : (blockIdx.x - nbA);
  const float4* __restrict__ qarr = taskA ? qarrA : qarrB;
  const int  nq    = taskA ? nqA : nqB;
  const int  ksel  = taskA ? 17 : 16;
  const int  ooff  = taskA ? 1  : 0;
  int*   __restrict__ oidx  = taskA ? oidxA  : oidxB;
  float* __restrict__ odist = taskA ? odistA : odistB;

  if (tid < QBLK){
    int qg = bq*QBLK + tid;
    qs[tid] = qarr[qg < nq ? qg : nq-1];   // clamp: all waves stay full
  }
  if (lane < QW) scnt[w][lane] = 0;
  __syncthreads();

  // -2*q in registers (e = fma(q2x,cx, fma(q2y,cy, fma(q2z,cz, cw))))
  float q2x[QW], q2y[QW], q2z[QW];
  #pragma unroll
  for (int q = 0; q < QW; ++q){
    float4 v = qs[w*QW + q];
    q2x[q] = -2.f*v.x; q2y[q] = -2.f*v.y; q2z[q] = -2.f*v.z;
  }

  // ---------------- pass 1: per-lane e-min per query (LDS-tiled) ---------
  float mn[QW];
  #pragma unroll
  for (int q = 0; q < QW; ++q) mn[q] = FLT_MAX;

  for (int t = 0; t < NTILES; ++t){
    #pragma unroll
    for (int u = 0; u < TILE/256; ++u)
      tile[tid + 256*u] = candP[t*TILE + tid + 256*u];
    __syncthreads();
    #pragma unroll 2
    for (int i = 0; i < TILE/64; ++i){
      float4 cv = tile[i*64 + lane];
      #pragma unroll
      for (int q = 0; q < QW; ++q){
        float e = fmaf(q2x[q], cv.x, fmaf(q2y[q], cv.y, fmaf(q2z[q], cv.z, cv.w)));
        mn[q] = fminf(mn[q], e);
      }
    }
    __syncthreads();
  }

  // threshold per query: ksel-th smallest lane-min + margin
  sort64fq(mn, lane);
  float T[QW];
  #pragma unroll
  for (int q = 0; q < QW; ++q) T[q] = __shfl(mn[q], ksel-1) + MARGIN;

  // ---------------- pass 2: collect survivors (LDS-tiled) ----------------
  for (int t = 0; t < NTILES; ++t){
    #pragma unroll
    for (int u = 0; u < TILE/256; ++u)
      tile[tid + 256*u] = candP[t*TILE + tid + 256*u];
    __syncthreads();
    #pragma unroll 2
    for (int i = 0; i < TILE/64; ++i){
      float4 cv = tile[i*64 + lane];
      const int j = t*TILE + i*64 + lane;
      #pragma unroll
      for (int q = 0; q < QW; ++q){
        float e = fmaf(q2x[q], cv.x, fmaf(q2y[q], cv.y, fmaf(q2z[q], cv.z, cv.w)));
        if (e <= T[q]){
          int ofs = atomicAdd(&scnt[w][q], 1);
          if (ofs < CAP) slots[w][q][ofs] = (ushort)j;
        }
      }
    }
    __syncthreads();
  }

  // ---------------- phase 3: exact per-query select ----------------
  for (int q = 0; q < QW; ++q){
    const int qgq = bq*QBLK + w*QW + q;
    if (qgq >= nq) continue;                 // wave-uniform
    const float4 qv = qs[w*QW + q];
    const int C = scnt[w][q];

    if (C <= CAP){
      int g = INT_MAX; float d2 = FLT_MAX;
      if (lane < C){
        g = slots[w][q][lane];
        float4 cp = candP[g];
        {
#pragma clang fp contract(off)
          float dot = qv.x*cp.x + qv.y*cp.y + qv.z*cp.z;
          d2 = (qv.w + cp.w) - 2.0f*dot;
        }
      }
      sort64pair(d2, g, lane);
      if (lane >= ooff && lane < ooff + KOUT){
        float4 cp = candP[g];
        float dist;
        {
#pragma clang fp contract(off)
          float dx = qv.x-cp.x, dy = qv.y-cp.y, dz = qv.z-cp.z;
          dist = (dx*dx + dy*dy) + dz*dz;
        }
        oidx[(size_t)qgq*KOUT + (lane-ooff)]  = g;
        odist[(size_t)qgq*KOUT + (lane-ooff)] = dist;
      }
    } else if (lane == 0){
      // astronomically rare slot overflow: serial exact full scan
      float bd[KMAX]; int bi[KMAX];
      for (int t=0;t<ksel;t++){ bd[t]=FLT_MAX; bi[t]=INT_MAX; }
      float cmd = FLT_MAX; int cmi = INT_MAX;
      for (int jj = 0; jj < ncand; ++jj){
        float4 cp = candP[jj];
        float d2;
        {
#pragma clang fp contract(off)
          float dot = qv.x*cp.x + qv.y*cp.y + qv.z*cp.z;
          d2 = (qv.w + cp.w) - 2.0f*dot;
        }
        if (d2 < cmd || (d2 == cmd && jj < cmi)){
          int rt = 0; float rmd=-FLT_MAX; int rmi=-1;
          for (int t=0;t<ksel;t++){
            if (bd[t] > rmd || (bd[t]==rmd && bi[t]>rmi)){ rmd=bd[t]; rmi=bi[t]; rt=t; }
          }
          bd[rt]=d2; bi[rt]=jj;
          cmd=-FLT_MAX; cmi=-1;
          for (int t=0;t<ksel;t++){
            if (bd[t] > cmd || (bd[t]==cmd && bi[t]>cmi)){ cmd=bd[t]; cmi=bi[t]; }
          }
        }
      }
      for (int t=0;t<ksel;t++){
        int rt=-1; float mnd=FLT_MAX; int mni=INT_MAX;
        for (int u2=0;u2<ksel;u2++){
          if (bd[u2] < mnd || (bd[u2]==mnd && bi[u2]<mni)){ mnd=bd[u2]; mni=bi[u2]; rt=u2; }
        }
        bd[rt]=FLT_MAX; bi[rt]=INT_MAX;
        if (t >= ooff){
          float4 cp = candP[mni];
          float dist;
          {
#pragma clang fp contract(off)
            float dx=qv.x-cp.x, dy=qv.y-cp.y, dz=qv.z-cp.z;
            dist = (dx*dx + dy*dy) + dz*dz;
          }
          oidx[(size_t)qgq*KOUT + (t-ooff)]  = mni;
          odist[(size_t)qgq*KOUT + (t-ooff)] = dist;
        }
      }
    }
  }
}

// One message-passing block: out = self + lrelu(groupnorm(sum_k MLP(feat_k)))
// 16 threads per point: one neighbor per thread (coalesced idx/dists loads),
// 16-lane shfl_xor reduce (wave-aligned groups).
template<bool SELF_ONES>
__global__ __launch_bounds__(256)
void mp_kernel(const float* __restrict__ self_feat,
               const float* __restrict__ nb_src,
               const int* __restrict__ idx,
               const float* __restrict__ dists,
               const float* __restrict__ w1g, const float* __restrict__ b1g,
               const float* __restrict__ w2g, const float* __restrict__ b2g,
               const float* __restrict__ gam, const float* __restrict__ bet,
               float* __restrict__ out, int n){
  __shared__ float w1[H*H], b1v[H], w2[D*H], b2v[D], gm[D], bt[D];
  for (int t=threadIdx.x; t<H*H; t+=blockDim.x) w1[t]=w1g[t];
  if (threadIdx.x < H) b1v[threadIdx.x]=b1g[threadIdx.x];
  for (int t=threadIdx.x; t<D*H; t+=blockDim.x) w2[t]=w2g[t];
  if (threadIdx.x < D){
    b2v[threadIdx.x]=b2g[threadIdx.x];
    gm[threadIdx.x]=gam[threadIdx.x];
    bt[threadIdx.x]=bet[threadIdx.x];
  }
  __syncthreads();
  int tt = blockIdx.x*blockDim.x + threadIdx.x;
  int p = tt >> 4, k = tt & 15;
  if (p >= n) return;                  // whole 16-group exits together

  float s[D];
  #pragma unroll
  for (int j=0;j<D;j++) s[j] = SELF_ONES ? 1.0f : self_feat[p*D+j];

  int j = idx[p*KOUT+k];
  float dd = dists[p*KOUT+k];
  float f[H];
  #pragma unroll
  for (int c=0;c<D;c++) f[c]=s[c];
  #pragma unroll
  for (int c=0;c<D;c++) f[D+c]=nb_src[j*D+c];
  f[2*D]=dd;
  float h[H];
  #pragma unroll
  for (int o=0;o<H;o++){
    float acc=b1v[o];
    #pragma unroll
    for (int c=0;c<H;c++) acc += w1[o*H+c]*f[c];
    h[o]=lrelu(acc);
  }
  float msg[D];
  #pragma unroll
  for (int o=0;o<D;o++){
    float acc=b2v[o];
    #pragma unroll
    for (int c=0;c<H;c++) acc += w2[o*H+c]*h[c];
    msg[o]=acc;
  }

  // reduce the 16 partial msg vectors within the 16-lane group
  #pragma unroll
  for (int c=0;c<D;c++){
    msg[c] += __shfl_xor(msg[c], 1);
    msg[c] += __shfl_xor(msg[c], 2);
    msg[c] += __shfl_xor(msg[c], 4);
    msg[c] += __shfl_xor(msg[c], 8);
  }

  if (k == 0){
    float y[D];
    #pragma unroll
    for (int gi=0; gi<2; gi++){
      float m0=msg[gi*3+0], m1=msg[gi*3+1], m2=msg[gi*3+2];
      float mu = ((m0+m1)+m2) / 3.0f;
      float d0=m0-mu, d1=m1-mu, d2v=m2-mu;
      float var = ((d0*d0 + d1*d1) + d2v*d2v) / 3.0f;
      float inv = 1.0f / sqrtf(var + GEPS);
      y[gi*3+0] = d0*inv;
      y[gi*3+1] = d1*inv;
      y[gi*3+2] = d2v*inv;
    }
    #pragma unroll
    for (int c=0;c<D;c++){
      float vv = y[c]*gm[c] + bt[c];
      out[p*D+c] = s[c] + lrelu(vv);
    }
  }
}

extern "C" void kernel_launch(void* const* d_in, const int* in_sizes, int n_in,
                              void* d_out, int out_size, void* d_ws, size_t ws_size,
                              hipStream_t stream){
  const float* xyz       = (const float*)d_in[0];
  const float* atom_xyz  = (const float*)d_in[1];
  const float* atomtypes = (const float*)d_in[2];
  const float* tt_w1 = (const float*)d_in[5];
  const float* tt_b1 = (const float*)d_in[6];
  const float* tt_w2 = (const float*)d_in[7];
  const float* tt_b2 = (const float*)d_in[8];
  const float* aa_w1 = (const float*)d_in[9];
  const float* aa_b1 = (const float*)d_in[10];
  const float* aa_w2 = (const float*)d_in[11];
  const float* aa_b2 = (const float*)d_in[12];
  const float* aa_gamma = (const float*)d_in[13];
  const float* aa_beta  = (const float*)d_in[14];
  const float* em_w1 = (const float*)d_in[15];
  const float* em_b1 = (const float*)d_in[16];
  const float* em_w2 = (const float*)d_in[17];
  const float* em_b2 = (const float*)d_in[18];
  const float* em_gamma = (const float*)d_in[19];
  const float* em_beta  = (const float*)d_in[20];

  const int n_pts = in_sizes[0]/3;
  const int n_at  = in_sizes[1]/3;

  char* ws = (char*)d_ws;
  float4* candP = (float4*)ws; ws += (size_t)MPAD*sizeof(float4);
  float4* ptsP  = (float4*)ws; ws += (size_t)n_pts*sizeof(float4);
  float* fa   = (float*)ws; ws += (size_t)n_at*D*4;
  float* fb   = (float*)ws; ws += (size_t)n_at*D*4;
  int*   idxA = (int*)ws;   ws += (size_t)n_at*KOUT*4;
  float* distA= (float*)ws; ws += (size_t)n_at*KOUT*4;
  int*   idxP = (int*)ws;   ws += (size_t)n_pts*KOUT*4;
  float* distP= (float*)ws; ws += (size_t)n_pts*KOUT*4;
  float* ea   = (float*)ws; ws += (size_t)n_pts*D*4;
  float* eb   = (float*)ws; ws += (size_t)n_pts*D*4;
  float* outf = (float*)d_out;

  const int nprep = (MPAD > n_pts ? MPAD : n_pts);
  prep_kernel<<<(nprep+255)/256,256,0,stream>>>(
      atom_xyz, xyz, atomtypes, tt_w1, tt_b1, tt_w2, tt_b2,
      candP, ptsP, fa, n_at, n_pts);

  // ---- fused KNN: blocks [0,nbA) = atom-atom k=17 drop-self;
  //                 blocks [nbA,nbA+nbB) = point-atom k=16 ----
  const int nbA = (n_at  + QBLK - 1) / QBLK;
  const int nbB = (n_pts + QBLK - 1) / QBLK;
  knn9_kernel<<<nbA + nbB,256,0,stream>>>(
      candP, n_at, candP, n_at, nbA, ptsP, n_pts,
      idxA, distA, idxP, distP);

  mp_kernel<false><<<(n_at*16+255)/256,256,0,stream>>>(fa, fa, idxA, distA,
      aa_w1+0*H*H, aa_b1+0*H, aa_w2+0*D*H, aa_b2+0*D, aa_gamma+0*D, aa_beta+0*D, fb, n_at);
  mp_kernel<false><<<(n_at*16+255)/256,256,0,stream>>>(fb, fb, idxA, distA,
      aa_w1+1*H*H, aa_b1+1*H, aa_w2+1*D*H, aa_b2+1*D, aa_gamma+1*D, aa_beta+1*D, fa, n_at);
  mp_kernel<false><<<(n_at*16+255)/256,256,0,stream>>>(fa, fa, idxA, distA,
      aa_w1+2*H*H, aa_b1+2*H, aa_w2+2*D*H, aa_b2+2*D, aa_gamma+2*D, aa_beta+2*D, fb, n_at);
  // final atom features in fb

  mp_kernel<true ><<<(n_pts*16+255)/256,256,0,stream>>>(nullptr, fb, idxP, distP,
      em_w1+0*H*H, em_b1+0*H, em_w2+0*D*H, em_b2+0*D, em_gamma+0*D, em_beta+0*D, ea, n_pts);
  mp_kernel<false><<<(n_pts*16+255)/256,256,0,stream>>>(ea, fb, idxP, distP,
      em_w1+1*H*H, em_b1+1*H, em_w2+1*D*H, em_b2+1*D, em_gamma+1*D, em_beta+1*D, eb, n_pts);
  mp_kernel<false><<<(n_pts*16+255)/256,256,0,stream>>>(eb, fb, idxP, distP,
      em_w1+2*H*H, em_b1+2*H, em_w2+2*D*H, em_b2+2*D, em_gamma+2*D, em_beta+2*D, outf, n_pts);
}